// Round 7
// baseline (4011.090 us; speedup 1.0000x reference)
//
#include <hip/hip_runtime.h>
#include <hip/hip_bf16.h>
#include <math.h>

// Problem dims (fixed by reference)
#define T_STEPS 512
#define BATCH   64
#define DIN     256
#define HID     1024
#define DOUT    256
#define NBLK    64      // persistent blocks (1 per CU, grid << 256 CUs)
#define NFLAG   (NBLK * 4)   // per-WAVE flags, contiguous

typedef __attribute__((ext_vector_type(8))) short    bf16x8;
typedef __attribute__((ext_vector_type(4))) float    f32x4;
typedef unsigned long long ull;

static __device__ __forceinline__ unsigned short f2bf(float f) {
    union { float f; unsigned u; } v; v.f = f;
    unsigned u = v.u;
    u += 0x7fff + ((u >> 16) & 1);   // round-to-nearest-even
    return (unsigned short)(u >> 16);
}
static __device__ __forceinline__ float bf2f(unsigned short h) {
    union { unsigned u; float f; } v; v.u = ((unsigned)h) << 16; return v.f;
}

// Coherent (cross-XCD) ops: agent-scope relaxed atomics lower to sc0|sc1
// (L2-bypass / write-through to MALL). Protocol correctness proven R4/R6.
static __device__ __forceinline__ ull coh_load8(const ull* p) {
    return __hip_atomic_load(p, __ATOMIC_RELAXED, __HIP_MEMORY_SCOPE_AGENT);
}
static __device__ __forceinline__ void coh_store8(ull* p, ull v) {
    __hip_atomic_store(p, v, __ATOMIC_RELAXED, __HIP_MEMORY_SCOPE_AGENT);
}
static __device__ __forceinline__ unsigned coh_load4(const unsigned* p) {
    return __hip_atomic_load(p, __ATOMIC_RELAXED, __HIP_MEMORY_SCOPE_AGENT);
}
static __device__ __forceinline__ void coh_store4(unsigned* p, unsigned v) {
    __hip_atomic_store(p, v, __ATOMIC_RELAXED, __HIP_MEMORY_SCOPE_AGENT);
}

// ---------------- convert kernels ----------------
__global__ __launch_bounds__(256) void convert_x(const float* __restrict__ x,
                                                 unsigned short* __restrict__ xb) {
    size_t i = ((size_t)blockIdx.x * 256 + threadIdx.x) * 4;
    float4 v = *(const float4*)(x + i);
    ushort4 o;
    o.x = f2bf(v.x); o.y = f2bf(v.y); o.z = f2bf(v.z); o.w = f2bf(v.w);
    *(ushort4*)(xb + i) = o;
}

__global__ __launch_bounds__(256) void convert_wxt(const float* __restrict__ Wx,
                                                   unsigned short* __restrict__ wxtb) {
    int o = blockIdx.x * 256 + threadIdx.x;  // 262144 total
    int d = o & (DIN - 1);
    int j = o >> 8;
    wxtb[(size_t)j * DIN + d] = f2bf(Wx[(size_t)d * HID + j]);
}

// ---------------- pre = x @ Wx + b, written in CONSUMER FRAGMENT LAYOUT ----------
__global__ __launch_bounds__(256) void gemm_pre(const unsigned short* __restrict__ xb,
                                                const unsigned short* __restrict__ wxtb,
                                                const float* __restrict__ bias,
                                                ull* __restrict__ pre_r) {
    int t  = blockIdx.x;
    int nb = blockIdx.y * 64;
    int wave = threadIdx.x >> 6, lane = threadIdx.x & 63;
    int l15 = lane & 15, lkq = lane >> 4;

    f32x4 acc[4] = {};
    const unsigned short* aptr = xb + (size_t)(t * 64 + wave * 16 + l15) * DIN + lkq * 8;
#pragma unroll
    for (int ks = 0; ks < DIN / 32; ++ks) {
        bf16x8 a = *(const bf16x8*)(aptr + ks * 32);
#pragma unroll
        for (int nt = 0; nt < 4; ++nt) {
            const unsigned short* bp =
                wxtb + (size_t)(nb + nt * 16 + l15) * DIN + ks * 32 + lkq * 8;
            bf16x8 b = *(const bf16x8*)bp;
            acc[nt] = __builtin_amdgcn_mfma_f32_16x16x32_bf16(a, b, acc[nt], 0, 0, 0);
        }
    }
#pragma unroll
    for (int nt = 0; nt < 4; ++nt) {
        int blk = blockIdx.y * 4 + nt;
        float bb = bias[blk * 16 + l15];
        union { ushort4 s; ull u; } o;
        o.s.x = f2bf(acc[nt][0] + bb);
        o.s.y = f2bf(acc[nt][1] + bb);
        o.s.z = f2bf(acc[nt][2] + bb);
        o.s.w = f2bf(acc[nt][3] + bb);
        pre_r[(((size_t)(t * 64 + blk) * 4 + wave) * 64 + lane)] = o.u;
    }
}

// ---------------- persistent recurrence kernel ----------------
// grid = 64 blocks x 256 threads; block k owns h columns [16k,16k+16).
// WAVE-AUTONOMOUS loop: 256 per-wave flags; no __syncthreads in the loop.
// Per wave per step: poll 256 flags (4 coalesced lane-loads + ballots) ->
// deep-prefetch 64 sc1 A-frag loads into registers -> 32 MFMA -> tanh ->
// wave-private LDS repack (lgkm only) -> coalesced sc1 store -> per-wave
// vmcnt(0) drain (workgroup release fence = waitcnt, no cache walk) -> flag.
__global__ __launch_bounds__(256, 1) void rnn_persistent(const float* __restrict__ Wh,
                                                         const ull* __restrict__ pre_r,
                                                         unsigned short* __restrict__ hbuf,
                                                         unsigned* __restrict__ flags) {
    __shared__ unsigned short ldsB[32 * 64 * 8];   // 32 KB, Wh B-frags
    __shared__ unsigned short ldsC[4][16 * 16];    // per-wave 512B repack region
    const int cb = blockIdx.x * 16;
    const int bx = blockIdx.x;
    const int tid = threadIdx.x;

    // Stage + swizzle Wh[:, cb:cb+16) into B-frag layout (one time).
    for (int p = tid; p < 32 * 64; p += 256) {
        int ks = p >> 6, L = p & 63;
        int k0 = ks * 32 + ((L >> 4) * 8);
        int col = cb + (L & 15);
#pragma unroll
        for (int j = 0; j < 8; ++j)
            ldsB[p * 8 + j] = f2bf(Wh[(size_t)(k0 + j) * HID + col]);
    }
    __syncthreads();   // ldsB visible to all waves (only barrier in the kernel)

    const int w = tid >> 6, lane = tid & 63;
    const int l15 = lane & 15, lkq = lane >> 4;

    // Per-thread h-store target (8B unit) in A-fragment layout (R6-verified):
    const size_t st_unit =
        (((((size_t)(tid >> 6) * 32 + (bx >> 1)) << 6) +
          ((((bx & 1) * 2 + ((tid >> 1) & 1)) << 4) + ((tid >> 2) & 15))) << 1) + (tid & 1);

    const ull* myPre = pre_r + ((size_t)bx * 4 + w) * 64 + lane;
#define PRE_AT(t) myPre[(size_t)(t) * 64 * 4 * 64]

    const int myFlag = bx * 4 + w;

    // t = 0: h1 = tanh(pre[0]) (h0 == 0), per-wave publish.
    {
        union { ushort4 s; ull u; } pv; pv.u = PRE_AT(0);
        ldsC[w][(lkq * 4 + 0) * 16 + l15] = f2bf(tanhf(bf2f(pv.s.x)));
        ldsC[w][(lkq * 4 + 1) * 16 + l15] = f2bf(tanhf(bf2f(pv.s.y)));
        ldsC[w][(lkq * 4 + 2) * 16 + l15] = f2bf(tanhf(bf2f(pv.s.z)));
        ldsC[w][(lkq * 4 + 3) * 16 + l15] = f2bf(tanhf(bf2f(pv.s.w)));
        ull v = ((const ull*)&ldsC[w][0])[lane];   // compiler emits lgkm wait
        coh_store8((ull*)(hbuf + (size_t)BATCH * HID) + st_unit, v);
        __builtin_amdgcn_fence(__ATOMIC_RELEASE, "workgroup");  // waitcnt-only drain
        if (lane == 0) coh_store4(&flags[myFlag], 1u);
    }

    ull pv_next = PRE_AT(1);

    for (int t = 1; t <= 510; ++t) {
        union { ushort4 s; ull u; } pvc; pvc.u = pv_next;
        if (t < 510) pv_next = PRE_AT(t + 1);

        // Poll ALL 256 wave-flags (contiguous; 4 coalesced lane-loads).
        {
            const unsigned tt = (unsigned)t;
            for (;;) {
                unsigned v0 = coh_load4(&flags[lane]);
                unsigned v1 = coh_load4(&flags[lane + 64]);
                unsigned v2 = coh_load4(&flags[lane + 128]);
                unsigned v3 = coh_load4(&flags[lane + 192]);
                bool ok = (v0 >= tt) & (v1 >= tt) & (v2 >= tt) & (v3 >= tt);
                if (__ballot(ok) == ~0ull) break;
                __builtin_amdgcn_s_sleep(1);
            }
        }

        const ull* hcu = (const ull*)(hbuf + (size_t)(t & 1) * BATCH * HID);
        ull*       hnu = (ull*)(hbuf + (size_t)((t + 1) & 1) * BATCH * HID);

        // Deep prefetch: all 64 A-frag loads issued before any MFMA.
        const ull* au = hcu + (((size_t)w * 32) << 7) + lane * 2;
        ull ar[64];
#pragma unroll
        for (int ks = 0; ks < 32; ++ks) {
            ar[2 * ks]     = coh_load8(au + ((size_t)ks << 7));
            ar[2 * ks + 1] = coh_load8(au + ((size_t)ks << 7) + 1);
        }

        f32x4 acc0 = {}, acc1 = {};
#pragma unroll
        for (int ks = 0; ks < 32; ks += 2) {
            union { ull u[2]; bf16x8 v; } a0, a1;
            a0.u[0] = ar[2 * ks];     a0.u[1] = ar[2 * ks + 1];
            a1.u[0] = ar[2 * ks + 2]; a1.u[1] = ar[2 * ks + 3];
            bf16x8 w0 = *(const bf16x8*)&ldsB[((ks)*64 + lane) * 8];
            bf16x8 w1 = *(const bf16x8*)&ldsB[((ks + 1) * 64 + lane) * 8];
            acc0 = __builtin_amdgcn_mfma_f32_16x16x32_bf16(a0.v, w0, acc0, 0, 0, 0);
            acc1 = __builtin_amdgcn_mfma_f32_16x16x32_bf16(a1.v, w1, acc1, 0, 0, 0);
        }
        f32x4 acc = acc0 + acc1;

        // Epilogue: tanh + wave-private LDS repack (no barrier) + sc1 store.
        ldsC[w][(lkq * 4 + 0) * 16 + l15] = f2bf(tanhf(acc[0] + bf2f(pvc.s.x)));
        ldsC[w][(lkq * 4 + 1) * 16 + l15] = f2bf(tanhf(acc[1] + bf2f(pvc.s.y)));
        ldsC[w][(lkq * 4 + 2) * 16 + l15] = f2bf(tanhf(acc[2] + bf2f(pvc.s.z)));
        ldsC[w][(lkq * 4 + 3) * 16 + l15] = f2bf(tanhf(acc[3] + bf2f(pvc.s.w)));
        ull v = ((const ull*)&ldsC[w][0])[lane];
        coh_store8(hnu + st_unit, v);

        if (t < 510) {
            __builtin_amdgcn_fence(__ATOMIC_RELEASE, "workgroup"); // vmcnt(0) drain only
            if (lane == 0) coh_store4(&flags[myFlag], (unsigned)(t + 1));
        }
    }
#undef PRE_AT
    // h_511 (== H[-2]) is in buf[1] (A-fragment layout); kernel end = device release.
}

// ---------------- y = h_final @ W2 + b2 (h in A-fragment layout) ----------------
__global__ __launch_bounds__(256) void out_gemm(const unsigned short* __restrict__ hfin,
                                                const float* __restrict__ W2,
                                                const float* __restrict__ b2,
                                                float* __restrict__ out) {
    int b = blockIdx.x;        // batch row, 64
    int j = threadIdx.x;       // out col, 256
    int g = b >> 4, m = b & 15;
    float acc = b2[j];
    for (int ks = 0; ks < 32; ++ks) {
#pragma unroll
        for (int lkq = 0; lkq < 4; ++lkq) {
            const unsigned short* ch =
                hfin + ((size_t)((((g * 32 + ks) << 6) + (lkq << 4) + m)) << 3);
            int k0 = ks * 32 + lkq * 8;
#pragma unroll
            for (int jj = 0; jj < 8; ++jj)
                acc = fmaf(bf2f(ch[jj]), W2[(size_t)(k0 + jj) * DOUT + j], acc);
        }
    }
    out[(size_t)b * DOUT + j] = acc;
}

extern "C" void kernel_launch(void* const* d_in, const int* in_sizes, int n_in,
                              void* d_out, int out_size, void* d_ws, size_t ws_size,
                              hipStream_t stream) {
    const float* x  = (const float*)d_in[0];
    const float* Wx = (const float*)d_in[1];
    const float* Wh = (const float*)d_in[2];
    const float* b  = (const float*)d_in[3];
    const float* W2 = (const float*)d_in[4];
    const float* b2 = (const float*)d_in[5];
    float* out = (float*)d_out;

    // workspace carve (~81 MB)
    char* ws = (char*)d_ws;
    unsigned*       flags = (unsigned*)ws;                                   // 1 KB (256 flags)
    unsigned short* hbuf  = (unsigned short*)(ws + 4096);                    // 256 KB
    unsigned short* xb    = (unsigned short*)(ws + 4096 + 2 * BATCH * HID * 2); // 16 MB
    unsigned short* wxtb  = xb + (size_t)T_STEPS * BATCH * DIN;              // 0.5 MB
    ull*            pre_r = (ull*)(wxtb + (size_t)HID * DIN);                // 64 MB

    (void)hipMemsetAsync(flags, 0, 4096, stream);
    convert_x<<<8192, 256, 0, stream>>>(x, xb);
    convert_wxt<<<1024, 256, 0, stream>>>(Wx, wxtb);
    gemm_pre<<<dim3(512, 16), 256, 0, stream>>>(xb, wxtb, b, pre_r);
    rnn_persistent<<<NBLK, 256, 0, stream>>>(Wh, pre_r, hbuf, flags);
    out_gemm<<<64, 256, 0, stream>>>(hbuf + (size_t)BATCH * HID, W2, b2, out);
}

// Round 8
// 2480.570 us; speedup vs baseline: 1.6170x; 1.6170x over previous
//
#include <hip/hip_runtime.h>
#include <hip/hip_bf16.h>
#include <math.h>

// Problem dims (fixed by reference)
#define T_STEPS 512
#define BATCH   64
#define DIN     256
#define HID     1024
#define DOUT    256
#define NBLK    64      // persistent blocks (1 per CU)

typedef __attribute__((ext_vector_type(8))) short    bf16x8;
typedef __attribute__((ext_vector_type(4))) float    f32x4;
typedef unsigned long long ull;

static __device__ __forceinline__ unsigned short f2bf(float f) {
    union { float f; unsigned u; } v; v.f = f;
    unsigned u = v.u;
    u += 0x7fff + ((u >> 16) & 1);   // round-to-nearest-even
    return (unsigned short)(u >> 16);
}
static __device__ __forceinline__ float bf2f(unsigned short h) {
    union { unsigned u; float f; } v; v.u = ((unsigned)h) << 16; return v.f;
}

// Coherent (cross-XCD) ops: agent-scope relaxed atomics lower to sc0|sc1
// (L2-bypass / write-through to MALL). Protocol correctness proven R4/R6.
static __device__ __forceinline__ ull coh_load8(const ull* p) {
    return __hip_atomic_load(p, __ATOMIC_RELAXED, __HIP_MEMORY_SCOPE_AGENT);
}
static __device__ __forceinline__ void coh_store8(ull* p, ull v) {
    __hip_atomic_store(p, v, __ATOMIC_RELAXED, __HIP_MEMORY_SCOPE_AGENT);
}
static __device__ __forceinline__ unsigned coh_load4(const unsigned* p) {
    return __hip_atomic_load(p, __ATOMIC_RELAXED, __HIP_MEMORY_SCOPE_AGENT);
}
static __device__ __forceinline__ void coh_store4(unsigned* p, unsigned v) {
    __hip_atomic_store(p, v, __ATOMIC_RELAXED, __HIP_MEMORY_SCOPE_AGENT);
}

// ---------------- convert kernels ----------------
__global__ __launch_bounds__(256) void convert_x(const float* __restrict__ x,
                                                 unsigned short* __restrict__ xb) {
    size_t i = ((size_t)blockIdx.x * 256 + threadIdx.x) * 4;
    float4 v = *(const float4*)(x + i);
    ushort4 o;
    o.x = f2bf(v.x); o.y = f2bf(v.y); o.z = f2bf(v.z); o.w = f2bf(v.w);
    *(ushort4*)(xb + i) = o;
}

__global__ __launch_bounds__(256) void convert_wxt(const float* __restrict__ Wx,
                                                   unsigned short* __restrict__ wxtb) {
    int o = blockIdx.x * 256 + threadIdx.x;  // 262144 total
    int d = o & (DIN - 1);
    int j = o >> 8;
    wxtb[(size_t)j * DIN + d] = f2bf(Wx[(size_t)d * HID + j]);
}

// ---------------- pre = x @ Wx + b, written in CONSUMER FRAGMENT LAYOUT ----------
__global__ __launch_bounds__(256) void gemm_pre(const unsigned short* __restrict__ xb,
                                                const unsigned short* __restrict__ wxtb,
                                                const float* __restrict__ bias,
                                                ull* __restrict__ pre_r) {
    int t  = blockIdx.x;
    int nb = blockIdx.y * 64;
    int wave = threadIdx.x >> 6, lane = threadIdx.x & 63;
    int l15 = lane & 15, lkq = lane >> 4;

    f32x4 acc[4] = {};
    const unsigned short* aptr = xb + (size_t)(t * 64 + wave * 16 + l15) * DIN + lkq * 8;
#pragma unroll
    for (int ks = 0; ks < DIN / 32; ++ks) {
        bf16x8 a = *(const bf16x8*)(aptr + ks * 32);
#pragma unroll
        for (int nt = 0; nt < 4; ++nt) {
            const unsigned short* bp =
                wxtb + (size_t)(nb + nt * 16 + l15) * DIN + ks * 32 + lkq * 8;
            bf16x8 b = *(const bf16x8*)bp;
            acc[nt] = __builtin_amdgcn_mfma_f32_16x16x32_bf16(a, b, acc[nt], 0, 0, 0);
        }
    }
#pragma unroll
    for (int nt = 0; nt < 4; ++nt) {
        int blk = blockIdx.y * 4 + nt;
        float bb = bias[blk * 16 + l15];
        union { ushort4 s; ull u; } o;
        o.s.x = f2bf(acc[nt][0] + bb);
        o.s.y = f2bf(acc[nt][1] + bb);
        o.s.z = f2bf(acc[nt][2] + bb);
        o.s.w = f2bf(acc[nt][3] + bb);
        pre_r[(((size_t)(t * 64 + blk) * 4 + wave) * 64 + lane)] = o.u;
    }
}

// ---------------- persistent recurrence kernel ----------------
// grid = 64 blocks x 256 threads; block k owns h columns [16k,16k+16).
// Per step (ONE barrier total):
//   all waves poll 64 contiguous flags (1 coalesced lane-load + ballot)
//   -> 2-stage pipelined sc1 A-frag import (8 loads in flight) + 32 MFMA
//   -> tanh -> wave-private LDS repack (lgkm only) -> coalesced sc1 store
//   -> __syncthreads (per-wave vmcnt(0) drain before s_barrier) -> tid0 flag.
__global__ __launch_bounds__(256, 1) void rnn_persistent(const float* __restrict__ Wh,
                                                         const ull* __restrict__ pre_r,
                                                         unsigned short* __restrict__ hbuf,
                                                         unsigned* __restrict__ flags) {
    __shared__ unsigned short ldsB[32 * 64 * 8];   // 32 KB, Wh B-frags
    __shared__ unsigned short ldsC[4][16 * 16];    // per-wave 512B repack region
    const int cb = blockIdx.x * 16;
    const int bx = blockIdx.x;
    const int tid = threadIdx.x;

    // Stage + swizzle Wh[:, cb:cb+16) into B-frag layout (one time).
    for (int p = tid; p < 32 * 64; p += 256) {
        int ks = p >> 6, L = p & 63;
        int k0 = ks * 32 + ((L >> 4) * 8);
        int col = cb + (L & 15);
#pragma unroll
        for (int j = 0; j < 8; ++j)
            ldsB[p * 8 + j] = f2bf(Wh[(size_t)(k0 + j) * HID + col]);
    }
    __syncthreads();   // ldsB visible to all waves

    const int w = tid >> 6, lane = tid & 63;
    const int l15 = lane & 15, lkq = lane >> 4;

    // Per-thread h-store target (8B unit) in A-fragment layout (R6/R7-verified):
    const size_t st_unit =
        (((((size_t)(tid >> 6) * 32 + (bx >> 1)) << 6) +
          ((((bx & 1) * 2 + ((tid >> 1) & 1)) << 4) + ((tid >> 2) & 15))) << 1) + (tid & 1);

    const ull* myPre = pre_r + ((size_t)bx * 4 + w) * 64 + lane;
#define PRE_AT(t) myPre[(size_t)(t) * 64 * 4 * 64]

    // t = 0: h1 = tanh(pre[0]) (h0 == 0), wave-private repack + store.
    {
        union { ushort4 s; ull u; } pv; pv.u = PRE_AT(0);
        ldsC[w][(lkq * 4 + 0) * 16 + l15] = f2bf(tanhf(bf2f(pv.s.x)));
        ldsC[w][(lkq * 4 + 1) * 16 + l15] = f2bf(tanhf(bf2f(pv.s.y)));
        ldsC[w][(lkq * 4 + 2) * 16 + l15] = f2bf(tanhf(bf2f(pv.s.z)));
        ldsC[w][(lkq * 4 + 3) * 16 + l15] = f2bf(tanhf(bf2f(pv.s.w)));
        ull v = ((const ull*)&ldsC[w][0])[lane];   // lgkm wait only (wave-private)
        coh_store8((ull*)(hbuf + (size_t)BATCH * HID) + st_unit, v);
    }
    __syncthreads();   // each wave drains vmcnt(0) before s_barrier -> stores at MALL
    if (tid == 0) coh_store4(&flags[bx], 1u);

    ull pv_next = PRE_AT(1);

    for (int t = 1; t <= 510; ++t) {
        union { ushort4 s; ull u; } pvc; pvc.u = pv_next;
        if (t < 510) pv_next = PRE_AT(t + 1);

        // All waves poll the 64 contiguous flags: 1 coalesced load + ballot.
        {
            const unsigned tt = (unsigned)t;
            for (;;) {
                unsigned v = coh_load4(&flags[lane]);
                if (__ballot(v >= tt) == ~0ull) break;
                __builtin_amdgcn_s_sleep(1);
            }
        }

        const ull* hcu = (const ull*)(hbuf + (size_t)(t & 1) * BATCH * HID);
        ull*       hnu = (ull*)(hbuf + (size_t)((t + 1) & 1) * BATCH * HID);

        // 2-stage pipelined A-frag import: groups of 4 k-slices (8x8B loads),
        // prefetch group g+1 while MFMAing group g (~8 loads in flight).
        const ull* au = hcu + (((size_t)w * 32) << 7) + lane * 2;
        ull ar[8], nx[8];
#pragma unroll
        for (int j = 0; j < 4; ++j) {
            ar[2 * j]     = coh_load8(au + ((size_t)j << 7));
            ar[2 * j + 1] = coh_load8(au + ((size_t)j << 7) + 1);
        }
        f32x4 acc0 = {}, acc1 = {};
#pragma unroll
        for (int g = 0; g < 8; ++g) {
            if (g < 7) {
#pragma unroll
                for (int j = 0; j < 4; ++j) {
                    int ks = (g + 1) * 4 + j;
                    nx[2 * j]     = coh_load8(au + ((size_t)ks << 7));
                    nx[2 * j + 1] = coh_load8(au + ((size_t)ks << 7) + 1);
                }
            }
#pragma unroll
            for (int j = 0; j < 4; j += 2) {
                int ks = g * 4 + j;
                union { ull u[2]; bf16x8 v; } a0, a1;
                a0.u[0] = ar[2 * j];     a0.u[1] = ar[2 * j + 1];
                a1.u[0] = ar[2 * j + 2]; a1.u[1] = ar[2 * j + 3];
                bf16x8 w0 = *(const bf16x8*)&ldsB[((ks)*64 + lane) * 8];
                bf16x8 w1 = *(const bf16x8*)&ldsB[((ks + 1) * 64 + lane) * 8];
                acc0 = __builtin_amdgcn_mfma_f32_16x16x32_bf16(a0.v, w0, acc0, 0, 0, 0);
                acc1 = __builtin_amdgcn_mfma_f32_16x16x32_bf16(a1.v, w1, acc1, 0, 0, 0);
            }
            if (g < 7) {
#pragma unroll
                for (int j = 0; j < 8; ++j) ar[j] = nx[j];
            }
        }
        f32x4 acc = acc0 + acc1;

        // Epilogue: tanh + wave-private LDS repack (no barrier) + sc1 store.
        ldsC[w][(lkq * 4 + 0) * 16 + l15] = f2bf(tanhf(acc[0] + bf2f(pvc.s.x)));
        ldsC[w][(lkq * 4 + 1) * 16 + l15] = f2bf(tanhf(acc[1] + bf2f(pvc.s.y)));
        ldsC[w][(lkq * 4 + 2) * 16 + l15] = f2bf(tanhf(acc[2] + bf2f(pvc.s.z)));
        ldsC[w][(lkq * 4 + 3) * 16 + l15] = f2bf(tanhf(acc[3] + bf2f(pvc.s.w)));
        ull v = ((const ull*)&ldsC[w][0])[lane];
        coh_store8(hnu + st_unit, v);

        if (t < 510) {
            __syncthreads();   // ONE barrier/step: all waves' stores drained
            if (tid == 0) coh_store4(&flags[bx], (unsigned)(t + 1));
        }
    }
#undef PRE_AT
    // h_511 (== H[-2]) is in buf[1] (A-fragment layout); kernel end = device release.
}

// ---------------- y = h_final @ W2 + b2 (h in A-fragment layout) ----------------
__global__ __launch_bounds__(256) void out_gemm(const unsigned short* __restrict__ hfin,
                                                const float* __restrict__ W2,
                                                const float* __restrict__ b2,
                                                float* __restrict__ out) {
    int b = blockIdx.x;        // batch row, 64
    int j = threadIdx.x;       // out col, 256
    int g = b >> 4, m = b & 15;
    float acc = b2[j];
    for (int ks = 0; ks < 32; ++ks) {
#pragma unroll
        for (int lkq = 0; lkq < 4; ++lkq) {
            const unsigned short* ch =
                hfin + ((size_t)((((g * 32 + ks) << 6) + (lkq << 4) + m)) << 3);
            int k0 = ks * 32 + lkq * 8;
#pragma unroll
            for (int jj = 0; jj < 8; ++jj)
                acc = fmaf(bf2f(ch[jj]), W2[(size_t)(k0 + jj) * DOUT + j], acc);
        }
    }
    out[(size_t)b * DOUT + j] = acc;
}

extern "C" void kernel_launch(void* const* d_in, const int* in_sizes, int n_in,
                              void* d_out, int out_size, void* d_ws, size_t ws_size,
                              hipStream_t stream) {
    const float* x  = (const float*)d_in[0];
    const float* Wx = (const float*)d_in[1];
    const float* Wh = (const float*)d_in[2];
    const float* b  = (const float*)d_in[3];
    const float* W2 = (const float*)d_in[4];
    const float* b2 = (const float*)d_in[5];
    float* out = (float*)d_out;

    // workspace carve (~81 MB)
    char* ws = (char*)d_ws;
    unsigned*       flags = (unsigned*)ws;                                   // 256 B (64 flags)
    unsigned short* hbuf  = (unsigned short*)(ws + 4096);                    // 256 KB
    unsigned short* xb    = (unsigned short*)(ws + 4096 + 2 * BATCH * HID * 2); // 16 MB
    unsigned short* wxtb  = xb + (size_t)T_STEPS * BATCH * DIN;              // 0.5 MB
    ull*            pre_r = (ull*)(wxtb + (size_t)HID * DIN);                // 64 MB

    (void)hipMemsetAsync(flags, 0, 4096, stream);
    convert_x<<<8192, 256, 0, stream>>>(x, xb);
    convert_wxt<<<1024, 256, 0, stream>>>(Wx, wxtb);
    gemm_pre<<<dim3(512, 16), 256, 0, stream>>>(xb, wxtb, b, pre_r);
    rnn_persistent<<<NBLK, 256, 0, stream>>>(Wh, pre_r, hbuf, flags);
    out_gemm<<<64, 256, 0, stream>>>(hbuf + (size_t)BATCH * HID, W2, b2, out);
}

// Round 9
// 1583.732 us; speedup vs baseline: 2.5327x; 1.5663x over previous
//
#include <hip/hip_runtime.h>
#include <hip/hip_bf16.h>
#include <math.h>

// Problem dims (fixed by reference)
#define T_STEPS 512
#define BATCH   64
#define DIN     256
#define HID     1024
#define DOUT    256
#define NBLK    64      // rnn blocks: 4 row-groups x 16 col-groups

typedef __attribute__((ext_vector_type(8))) short    bf16x8;
typedef __attribute__((ext_vector_type(4))) float    f32x4;
typedef __attribute__((ext_vector_type(4))) int      i32x4;
typedef unsigned long long ull;

static __device__ __forceinline__ unsigned short f2bf(float f) {
    union { float f; unsigned u; } v; v.f = f;
    unsigned u = v.u;
    u += 0x7fff + ((u >> 16) & 1);   // round-to-nearest-even
    return (unsigned short)(u >> 16);
}
static __device__ __forceinline__ float bf2f(unsigned short h) {
    union { unsigned u; float f; } v; v.u = ((unsigned)h) << 16; return v.f;
}

// Coherent (cross-XCD) ops: agent-scope relaxed atomics -> sc0|sc1 (L2-bypass /
// write-through to MALL). Protocol correctness proven R4/R6/R7/R8.
static __device__ __forceinline__ void coh_store8(ull* p, ull v) {
    __hip_atomic_store(p, v, __ATOMIC_RELAXED, __HIP_MEMORY_SCOPE_AGENT);
}
static __device__ __forceinline__ unsigned coh_load4(const unsigned* p) {
    return __hip_atomic_load(p, __ATOMIC_RELAXED, __HIP_MEMORY_SCOPE_AGENT);
}
static __device__ __forceinline__ void coh_store4(unsigned* p, unsigned v) {
    __hip_atomic_store(p, v, __ATOMIC_RELAXED, __HIP_MEMORY_SCOPE_AGENT);
}

// ---------------- convert Wx -> WxT bf16 ----------------
__global__ __launch_bounds__(256) void convert_wxt(const float* __restrict__ Wx,
                                                   unsigned short* __restrict__ wxtb) {
    int o = blockIdx.x * 256 + threadIdx.x;  // 262144 total
    int d = o & (DIN - 1);
    int j = o >> 8;
    wxtb[(size_t)j * DIN + d] = f2bf(Wx[(size_t)d * HID + j]);
}

// ---------------- pre = x @ Wx + b, in the rnn consumer's unit layout ----------
// 8-B unit for (t, block bx=r*16+c, wave w, lane=(q<<5|p<<4|m)):
//   4 bf16 = pre[t][row 16r+m][cols 64c+16w+8p+4q .. +4)
__global__ __launch_bounds__(256) void gemm_pre(const float* __restrict__ x,
                                                const unsigned short* __restrict__ wxtb,
                                                const float* __restrict__ bias,
                                                ull* __restrict__ pre_r) {
    __shared__ unsigned short ldsP[64 * 68];   // 64 rows x 64 cols bf16, stride 68
    int t = blockIdx.x, y = blockIdx.y;        // rows [64t..), cols [64y..)
    int wave = threadIdx.x >> 6, lane = threadIdx.x & 63;
    int l15 = lane & 15, lkq = lane >> 4;
    int nb = y * 64;

    f32x4 acc[4] = {};
    const float* aptr = x + (size_t)(t * 64 + wave * 16 + l15) * DIN + lkq * 8;
#pragma unroll
    for (int ks = 0; ks < 8; ++ks) {
        float4 f0 = *(const float4*)(aptr + ks * 32);
        float4 f1 = *(const float4*)(aptr + ks * 32 + 4);
        union { unsigned short s[8]; bf16x8 h; } ua;
        ua.s[0] = f2bf(f0.x); ua.s[1] = f2bf(f0.y); ua.s[2] = f2bf(f0.z); ua.s[3] = f2bf(f0.w);
        ua.s[4] = f2bf(f1.x); ua.s[5] = f2bf(f1.y); ua.s[6] = f2bf(f1.z); ua.s[7] = f2bf(f1.w);
#pragma unroll
        for (int nt = 0; nt < 4; ++nt) {
            bf16x8 b = *(const bf16x8*)(wxtb + (size_t)(nb + nt * 16 + l15) * DIN + ks * 32 + lkq * 8);
            acc[nt] = __builtin_amdgcn_mfma_f32_16x16x32_bf16(ua.h, b, acc[nt], 0, 0, 0);
        }
    }
#pragma unroll
    for (int nt = 0; nt < 4; ++nt) {
        float bb = bias[nb + nt * 16 + l15];
#pragma unroll
        for (int reg = 0; reg < 4; ++reg)
            ldsP[(16 * wave + lkq * 4 + reg) * 68 + nt * 16 + l15] = f2bf(acc[nt][reg] + bb);
    }
    __syncthreads();
#pragma unroll
    for (int i = 0; i < 4; ++i) {
        int u = threadIdx.x + 256 * i;            // 1024 units
        int rr = u >> 8, w2 = (u >> 6) & 3, ln = u & 63;
        int mm = ln & 15, pp = (ln >> 4) & 1, qq = ln >> 5;
        int row = rr * 16 + mm, coloff = 16 * w2 + 8 * pp + 4 * qq;
        ull v = *(const ull*)&ldsP[row * 68 + coloff];
        pre_r[((size_t)(t * 64 + rr * 16 + y) * 4 + w2) * 64 + ln] = v;
    }
}

// ---------------- persistent recurrence kernel ----------------
// 64 blocks x 256 threads. Block bx: c=bx&15 (cols [64c..64c+64)), r=bx>>4
// (rows [16r..16r+16)). Wave w owns K range [256w..256w+256); its Wh slice
// (32 KB) lives in REGISTERS. h chunks (16B) in A-frag layout per row-group:
//   unit16 = r*2048 + ks*64 + lkq*16 + m  <->  h[16r+m][ks*32+lkq*8 .. +8)
// Per wave per step: early-start poll (16 wave-flags of its 4 producer blocks)
// -> 8 asm sc1 dwordx4 loads (one vmcnt window) -> 32 MFMA -> f32 partials to
// parity-LDS -> 1 barrier -> 4-wave reduce + pre + tanh -> coherent 8B store
// -> per-wave vmcnt drain -> wave flag. h triple-buffered (early-start safety:
// a t+2 writer transitively waited on ALL waves' t-flags via 2-level ancestry).
__global__ __launch_bounds__(256, 1) void rnn_persistent(const float* __restrict__ Wh,
                                                         const ull* __restrict__ pre_r,
                                                         unsigned short* __restrict__ hbuf,
                                                         unsigned* __restrict__ flags) {
    __shared__ float ldsR[2][4][16 * 68];   // [parity][wave][row*68+col] = 34816 B
    const int bx = blockIdx.x;
    const int c = bx & 15, r = bx >> 4;
    const int tid = threadIdx.x;
    const int w = tid >> 6, lane = tid & 63;
    const int l15 = lane & 15, lkq = lane >> 4;
    const int p = (lane >> 4) & 1, q = lane >> 5;
    const int m = l15;

    // One-time: B-fragments (Wh[k][col], k in wave range, cols 64c..64c+64) -> regs.
    bf16x8 bfr[8][4];
#pragma unroll
    for (int ksl = 0; ksl < 8; ++ksl)
#pragma unroll
        for (int nt = 0; nt < 4; ++nt) {
            union { unsigned short s[8]; bf16x8 h; } u;
            int k0 = w * 256 + ksl * 32 + lkq * 8;
            int col = c * 64 + nt * 16 + l15;
#pragma unroll
            for (int j = 0; j < 8; ++j)
                u.s[j] = f2bf(Wh[(size_t)(k0 + j) * HID + col]);
            bfr[ksl][nt] = u.h;
        }

    char* hb = (char*)hbuf;               // 3 buffers x 128 KB
    const char* hc = hb + 131072;         // read  at t=1 (h_1)
    char*       hn = hb + 2 * 131072;     // write at t=1 (h_2)
    char*       hx = hb;                  // write at t=2

    // This thread's h-store unit (8B): chunk (ks=2c+(w>>1), lkq=2(w&1)+p, m), half q
    const size_t st_unit8 =
        2 * ((size_t)r * 2048 + (size_t)(2 * c + (w >> 1)) * 64 + (2 * (w & 1) + p) * 16 + m) + q;

    const ull* myPre = pre_r + ((size_t)bx * 4 + w) * 64 + lane;
#define PRE_AT(t) myPre[(size_t)(t) * 16384]

    const int myFlag = (bx << 2) + w;
    const int pollIdx = r * 64 + 16 * w + l15;   // 16 wave-flags of 4 producer blocks

    // t = 0: h1 = tanh(pre0) (h0 == 0) -> buf1.
    {
        union { ushort4 s; ull u; } pv; pv.u = PRE_AT(0);
        union { ushort4 s; ull u; } hv;
        hv.s.x = f2bf(tanhf(bf2f(pv.s.x)));
        hv.s.y = f2bf(tanhf(bf2f(pv.s.y)));
        hv.s.z = f2bf(tanhf(bf2f(pv.s.z)));
        hv.s.w = f2bf(tanhf(bf2f(pv.s.w)));
        coh_store8((ull*)(hb + 131072) + st_unit8, hv.u);
        __builtin_amdgcn_fence(__ATOMIC_RELEASE, "workgroup");   // per-wave vmcnt drain
        if (lane == 0) coh_store4(&flags[myFlag], 1u);
    }

    ull pv_next = PRE_AT(1);

    for (int t = 1; t <= 510; ++t) {
        union { ushort4 s; ull u; } pvc; pvc.u = pv_next;
        if (t < 510) pv_next = PRE_AT(t + 1);

        // Early-start poll: wave w waits only for its k-range producers.
        {
            const unsigned tt = (unsigned)t;
            for (;;) {
                unsigned v = coh_load4(&flags[pollIdx]);
                if (__ballot(v >= tt) == ~0ull) break;
                __builtin_amdgcn_s_sleep(1);
            }
        }

        // A import: 8 x 16B L2-bypassing loads, ALL in flight, one vmcnt window.
        i32x4 a[8];
        const char* abase = hc + ((size_t)r * 2048 + (size_t)(8 * w) * 64 + lane) * 16;
#pragma unroll
        for (int ksl = 0; ksl < 8; ++ksl)
            asm volatile("global_load_dwordx4 %0, %1, off sc0 sc1"
                         : "=v"(a[ksl])
                         : "v"((const void*)(abase + (size_t)ksl * 1024)));
        asm volatile("s_waitcnt vmcnt(0)" ::: "memory");
        __builtin_amdgcn_sched_barrier(0);

        f32x4 acc0 = {}, acc1 = {}, acc2 = {}, acc3 = {};
#pragma unroll
        for (int ksl = 0; ksl < 8; ++ksl) {
            union { i32x4 i; bf16x8 h; } av; av.i = a[ksl];
            acc0 = __builtin_amdgcn_mfma_f32_16x16x32_bf16(av.h, bfr[ksl][0], acc0, 0, 0, 0);
            acc1 = __builtin_amdgcn_mfma_f32_16x16x32_bf16(av.h, bfr[ksl][1], acc1, 0, 0, 0);
            acc2 = __builtin_amdgcn_mfma_f32_16x16x32_bf16(av.h, bfr[ksl][2], acc2, 0, 0, 0);
            acc3 = __builtin_amdgcn_mfma_f32_16x16x32_bf16(av.h, bfr[ksl][3], acc3, 0, 0, 0);
        }

        // Partial sums -> parity LDS (row = lkq*4+reg, col = nt*16+l15).
        float* R = &ldsR[t & 1][w][0];
#pragma unroll
        for (int reg = 0; reg < 4; ++reg) {
            R[(lkq * 4 + reg) * 68 + l15]      = acc0[reg];
            R[(lkq * 4 + reg) * 68 + 16 + l15] = acc1[reg];
            R[(lkq * 4 + reg) * 68 + 32 + l15] = acc2[reg];
            R[(lkq * 4 + reg) * 68 + 48 + l15] = acc3[reg];
        }
        __syncthreads();   // the ONE barrier per step

        // Reduce across 4 waves, add pre, tanh, pack, coherent 8B store.
        const int coloff = 16 * w + 8 * p + 4 * q;
        f32x4 s;
        s  = *(const f32x4*)&ldsR[t & 1][0][m * 68 + coloff];
        s += *(const f32x4*)&ldsR[t & 1][1][m * 68 + coloff];
        s += *(const f32x4*)&ldsR[t & 1][2][m * 68 + coloff];
        s += *(const f32x4*)&ldsR[t & 1][3][m * 68 + coloff];
        union { ushort4 st; ull u; } hv;
        hv.st.x = f2bf(tanhf(s[0] + bf2f(pvc.s.x)));
        hv.st.y = f2bf(tanhf(s[1] + bf2f(pvc.s.y)));
        hv.st.z = f2bf(tanhf(s[2] + bf2f(pvc.s.z)));
        hv.st.w = f2bf(tanhf(s[3] + bf2f(pvc.s.w)));
        coh_store8((ull*)hn + st_unit8, hv.u);

        __builtin_amdgcn_fence(__ATOMIC_RELEASE, "workgroup");   // per-wave vmcnt drain
        if (t < 510 && lane == 0) coh_store4(&flags[myFlag], (unsigned)(t + 1));

        // rotate triple buffer
        const char* tmp = hc; hc = hn; hn = hx; hx = (char*)tmp;
    }
#undef PRE_AT
    // h_511 (== H[-2]) is in buf1; kernel end = implicit device release.
}

// ---------------- y = h_final @ W2 + b2 (h in group/A-frag chunk layout) --------
__global__ __launch_bounds__(256) void out_gemm(const unsigned short* __restrict__ hfin,
                                                const float* __restrict__ W2,
                                                const float* __restrict__ b2,
                                                float* __restrict__ out) {
    int b = blockIdx.x;        // batch row, 64
    int j = threadIdx.x;       // out col, 256
    int r = b >> 4, m = b & 15;
    float acc = b2[j];
    for (int ks = 0; ks < 32; ++ks) {
#pragma unroll
        for (int lkq = 0; lkq < 4; ++lkq) {
            const unsigned short* ch =
                hfin + ((size_t)(r * 2048 + ks * 64 + lkq * 16 + m)) * 8;
            int k0 = ks * 32 + lkq * 8;
#pragma unroll
            for (int jj = 0; jj < 8; ++jj)
                acc = fmaf(bf2f(ch[jj]), W2[(size_t)(k0 + jj) * DOUT + j], acc);
        }
    }
    out[(size_t)b * DOUT + j] = acc;
}

extern "C" void kernel_launch(void* const* d_in, const int* in_sizes, int n_in,
                              void* d_out, int out_size, void* d_ws, size_t ws_size,
                              hipStream_t stream) {
    const float* x  = (const float*)d_in[0];
    const float* Wx = (const float*)d_in[1];
    const float* Wh = (const float*)d_in[2];
    const float* b  = (const float*)d_in[3];
    const float* W2 = (const float*)d_in[4];
    const float* b2 = (const float*)d_in[5];
    float* out = (float*)d_out;

    // workspace carve (~68 MB)
    char* ws = (char*)d_ws;
    unsigned*       flags = (unsigned*)ws;                          // 1 KB (256 wave-flags)
    unsigned short* hbuf  = (unsigned short*)(ws + 4096);           // 3 x 128 KB
    unsigned short* wxtb  = (unsigned short*)(ws + 4096 + 393216);  // 0.5 MB
    ull*            pre_r = (ull*)(ws + 4096 + 393216 + 524288);    // 64 MB

    (void)hipMemsetAsync(flags, 0, 4096, stream);
    convert_wxt<<<1024, 256, 0, stream>>>(Wx, wxtb);
    gemm_pre<<<dim3(512, 16), 256, 0, stream>>>(x, wxtb, b, pre_r);
    rnn_persistent<<<NBLK, 256, 0, stream>>>(Wh, pre_r, hbuf, flags);
    out_gemm<<<64, 256, 0, stream>>>(hbuf + 65536, W2, b2, out);
}